// Round 10
// baseline (342.510 us; speedup 1.0000x reference)
//
#include <hip/hip_runtime.h>

#define N_TOK 16384
#define KCB   16384
#define DIM   256
#define HW    1024
#define DECAYF 0.8f
#define ONE_M_DECAY 0.2f
#define BETAF 0.25f
#define EPSF  1e-5f
#define STRIPS 8
#define KB_PER 16

typedef __attribute__((ext_vector_type(8))) short bf16x8;
typedef __attribute__((ext_vector_type(4))) float f32x4;

__device__ __forceinline__ float wave_reduce_sum(float s) {
    #pragma unroll
    for (int o = 32; o > 0; o >>= 1) s += __shfl_down(s, o);
    return s;
}

__device__ __forceinline__ unsigned short f2bf(float x) {
    union { float f; unsigned int u; } a; a.f = x;
    unsigned int r = a.u + 0x7fffu + ((a.u >> 16) & 1u);
    return (unsigned short)(r >> 16);
}

// ---- K_pre: fused {transpose z -> zf/Ah} + {Bh = bf16(w)} + {sum(cs)} ----
__global__ void k_pre(const float* __restrict__ z, float* __restrict__ zf,
                      unsigned short* __restrict__ Ah, const float* __restrict__ w,
                      unsigned short* __restrict__ Bh, const float* __restrict__ cs,
                      float* __restrict__ scal) {
    __shared__ float t[32][33];
    int blk = blockIdx.x;
    int tid = threadIdx.x;
    if (blk < 4096) {
        int b = blk >> 8, c0 = ((blk >> 5) & 7) * 32, h0 = (blk & 31) * 32;
        int jx = tid & 31, iy = tid >> 5;
        const float* zb = z + (size_t)b * DIM * HW;
        #pragma unroll
        for (int p = 0; p < 4; ++p) {
            int ci = iy + p * 8;
            t[ci][jx] = zb[(size_t)(c0 + ci) * HW + h0 + jx];
        }
        __syncthreads();
        #pragma unroll
        for (int p = 0; p < 4; ++p) {
            int hh = iy + p * 8;
            size_t idx = (size_t)(b * HW + h0 + hh) * DIM + c0 + jx;
            float v = t[jx][hh];
            zf[idx] = v;
            Ah[idx] = f2bf(v);
        }
    } else if (blk < 8192) {
        int wv = (blk - 4096) * 4 + (tid >> 6);
        int lane = tid & 63;
        float4 v = ((const float4*)(w + (size_t)wv * DIM))[lane];
        ushort4 h;
        h.x = f2bf(v.x); h.y = f2bf(v.y); h.z = f2bf(v.z); h.w = f2bf(v.w);
        ((ushort4*)(Bh + (size_t)wv * DIM))[lane] = h;
    } else {
        int i = (blk - 8192) * 256 + tid;
        int lane = tid & 63;
        float v = cs[i];
        v = wave_reduce_sum(v);
        if (lane == 0) atomicAdd(&scal[1], v);
    }
}

// ---- K3: bf16 MFMA GEMM (R8 structure, wnorm dropped). m201 phase order:
// ----     ds_read -> stage-issue -> barrier -> MFMA cluster -> vmcnt(0) -> barrier ----
__global__ __launch_bounds__(256, 2) void k_gemm_argmin(
    const unsigned short* __restrict__ Ah, const unsigned short* __restrict__ Bh,
    uint2* __restrict__ pout) {
    __shared__ unsigned short As[128 * 256];   // 64 KB, 16B-chunk pos = c ^ (row&7)
    __shared__ unsigned short Bs[2][128 * 32]; // 2 x 8 KB, 16B-chunk pos = c ^ (row&3)

    int tid  = threadIdx.x;
    int wave = tid >> 6, lane = tid & 63;
    int g16  = lane >> 4, r16 = lane & 15;
    int n0   = blockIdx.x * 128;
    int strip = blockIdx.y;

    #pragma unroll
    for (int i = 0; i < 16; ++i) {
        int s = (wave * 16 + i) * 64 + lane;
        int row = s >> 5, pos = s & 31;
        int c = pos ^ (row & 7);
        const unsigned int* ga = (const unsigned int*)(Ah + (size_t)(n0 + row) * 256 + c * 8);
        unsigned int* la = (unsigned int*)&As[(size_t)((wave * 16 + i) * 64) * 8];
        __builtin_amdgcn_global_load_lds((const __attribute__((address_space(1))) unsigned int*)ga,
                                         (__attribute__((address_space(3))) unsigned int*)la, 16, 0, 0);
    }

    auto stageB = [&](int kb, int ks, int buf) {
        int c0 = (strip * KB_PER + kb) * 128;
        #pragma unroll
        for (int j = 0; j < 2; ++j) {
            int s = (wave * 2 + j) * 64 + lane;
            int m = s >> 2, pk = (s & 3) ^ (m & 3);
            const unsigned int* gb = (const unsigned int*)(Bh + (size_t)(c0 + m) * 256 + ks * 32 + pk * 8);
            unsigned int* lb = (unsigned int*)&Bs[buf][(size_t)((wave * 2 + j) * 64) * 8];
            __builtin_amdgcn_global_load_lds((const __attribute__((address_space(1))) unsigned int*)gb,
                                             (__attribute__((address_space(3))) unsigned int*)lb, 16, 0, 0);
        }
    };

    stageB(0, 0, 0);

    asm volatile("s_waitcnt vmcnt(0)" ::: "memory");
    __builtin_amdgcn_s_barrier();
    asm volatile("" ::: "memory");

    unsigned int b1[16], b2[16];
    #pragma unroll
    for (int i = 0; i < 16; ++i) { b1[i] = 0xFFFFFFFFu; b2[i] = 0xFFFFFFFFu; }

    for (int kbi = 0; kbi < KB_PER; ++kbi) {
        f32x4 acc[4][4];
        #pragma unroll
        for (int mt = 0; mt < 4; ++mt)
            #pragma unroll
            for (int nt = 0; nt < 4; ++nt)
                acc[mt][nt] = (f32x4){0.f, 0.f, 0.f, 0.f};

        #pragma unroll
        for (int ks = 0; ks < 8; ++ks) {
            bf16x8 af[4], bfr[4];
            #pragma unroll
            for (int mt = 0; mt < 4; ++mt) {
                int row = (wave >> 1) * 64 + mt * 16 + r16;
                int pos = (ks * 4 + g16) ^ (row & 7);
                af[mt] = *(const bf16x8*)&As[(row * 32 + pos) * 8];
            }
            #pragma unroll
            for (int nt = 0; nt < 4; ++nt) {
                int row = (wave & 1) * 64 + nt * 16 + r16;
                int pk = g16 ^ (row & 3);
                bfr[nt] = *(const bf16x8*)&Bs[ks & 1][(row * 4 + pk) * 8];
            }
            if (!(kbi == KB_PER - 1 && ks == 7)) {
                int nk = (ks == 7) ? kbi + 1 : kbi;
                stageB(nk, (ks + 1) & 7, (ks + 1) & 1);
            }
            __builtin_amdgcn_s_barrier();
            __builtin_amdgcn_sched_barrier(0);
            __builtin_amdgcn_s_setprio(1);
            #pragma unroll
            for (int mt = 0; mt < 4; ++mt)
                #pragma unroll
                for (int nt = 0; nt < 4; ++nt)
                    acc[mt][nt] = __builtin_amdgcn_mfma_f32_16x16x32_bf16(af[mt], bfr[nt], acc[mt][nt], 0, 0, 0);
            __builtin_amdgcn_s_setprio(0);
            asm volatile("s_waitcnt vmcnt(0)" ::: "memory");
            __builtin_amdgcn_s_barrier();
            asm volatile("" ::: "memory");
        }

        unsigned int orv[4];
        #pragma unroll
        for (int nt = 0; nt < 4; ++nt)
            orv[nt] = (unsigned int)((kbi << 7) | ((wave & 1) << 6) | (nt << 4));
        #pragma unroll
        for (int mt = 0; mt < 4; ++mt)
            #pragma unroll
            for (int rg = 0; rg < 4; ++rg) {
                int i = mt * 4 + rg;
                #pragma unroll
                for (int nt = 0; nt < 4; ++nt) {
                    float s = fmaf(-2.0f, acc[mt][nt][rg], 0.0625f);
                    unsigned int u = (__float_as_uint(s) & 0xFFFFF800u) | orv[nt];
                    unsigned int t2 = b1[i] > u ? b1[i] : u;
                    b1[i] = b1[i] < u ? b1[i] : u;
                    b2[i] = b2[i] < t2 ? b2[i] : t2;
                }
            }
    }

    #pragma unroll
    for (int i = 0; i < 16; ++i) {
        unsigned int v1 = b1[i] | (unsigned int)r16;
        unsigned int v2 = b2[i] | (unsigned int)r16;
        #pragma unroll
        for (int off = 1; off < 16; off <<= 1) {
            unsigned int o1 = __shfl_xor((int)v1, off);
            unsigned int o2 = __shfl_xor((int)v2, off);
            unsigned int n1 = v1 < o1 ? v1 : o1;
            unsigned int hi = v1 < o1 ? o1 : v1;
            unsigned int lo = v2 < o2 ? v2 : o2;
            v1 = n1;
            v2 = hi < lo ? hi : lo;
        }
        b1[i] = v1; b2[i] = v2;
    }

    __syncthreads();
    unsigned int* red1 = (unsigned int*)Bs;
    unsigned int* red2 = red1 + 256;
    if (r16 == 0) {
        #pragma unroll
        for (int mt = 0; mt < 4; ++mt)
            #pragma unroll
            for (int rg = 0; rg < 4; ++rg) {
                int row = (wave >> 1) * 64 + mt * 16 + g16 * 4 + rg;
                red1[(wave & 1) * 128 + row] = b1[mt * 4 + rg];
                red2[(wave & 1) * 128 + row] = b2[mt * 4 + rg];
            }
    }
    __syncthreads();
    if (tid < 128) {
        unsigned int a1 = red1[tid], a2 = red2[tid];
        unsigned int c1 = red1[128 + tid], c2 = red2[128 + tid];
        unsigned int m1 = a1 < c1 ? a1 : c1;
        unsigned int hi = a1 < c1 ? c1 : a1;
        unsigned int lo = a2 < c2 ? a2 : c2;
        pout[(size_t)strip * N_TOK + n0 + tid] = make_uint2(m1, hi < lo ? hi : lo);
    }
}

// ---- K4: merge strips + exact rescore + counts + dmin + embed_sum atomic scatter ----
__global__ void k_select(const uint2* __restrict__ pout, const float* __restrict__ zf,
                         const float* __restrict__ w, int* __restrict__ tok,
                         float* __restrict__ counts, float* __restrict__ dmin,
                         float* __restrict__ embed_sum) {
    int n = blockIdx.x * 4 + (threadIdx.x >> 6);
    int lane = threadIdx.x & 63;
    unsigned int c1 = 0xFFFFFFFFu, c2 = 0xFFFFFFFFu;
    int s1 = 0, s2 = 0;
    #pragma unroll
    for (int s = 0; s < STRIPS; ++s) {
        uint2 p = pout[(size_t)s * N_TOK + n];
        if (p.x < c1)      { c2 = c1; s2 = s1; c1 = p.x; s1 = s; }
        else if (p.x < c2) { c2 = p.x; s2 = s; }
        if (p.y < c1)      { c2 = c1; s2 = s1; c1 = p.y; s1 = s; }
        else if (p.y < c2) { c2 = p.y; s2 = s; }
    }
    int code1 = (s1 << 11) | (int)(c1 & 0x7FFu);
    int code2 = (s2 << 11) | (int)(c2 & 0x7FFu);

    float4 zv = ((const float4*)(zf + (size_t)n * DIM))[lane];
    float4 w1 = ((const float4*)(w + (size_t)code1 * DIM))[lane];
    float4 w2 = ((const float4*)(w + (size_t)code2 * DIM))[lane];
    float ax = zv.x - w1.x, ay = zv.y - w1.y, az = zv.z - w1.z, aw = zv.w - w1.w;
    float bx = zv.x - w2.x, by = zv.y - w2.y, bz = zv.z - w2.z, bw = zv.w - w2.w;
    float d1 = ax * ax + ay * ay + az * az + aw * aw;
    float d2 = bx * bx + by * by + bz * bz + bw * bw;
    d1 = wave_reduce_sum(d1);
    d2 = wave_reduce_sum(d2);
    d1 = __shfl(d1, 0);
    d2 = __shfl(d2, 0);
    bool take2 = (d2 < d1) || (d2 == d1 && code2 < code1);
    int tokv = take2 ? code2 : code1;
    if (lane == 0) {
        dmin[n] = take2 ? d2 : d1;
        atomicAdd(&counts[tokv], 1.0f);
        tok[n] = tokv;
    }
    float* es = embed_sum + (size_t)tokv * DIM + lane * 4;
    atomicAdd(es + 0, zv.x);
    atomicAdd(es + 1, zv.y);
    atomicAdd(es + 2, zv.z);
    atomicAdd(es + 3, zv.w);
}

// ---- K_post: fused {embed outputs} + {write_out} + {stats} ----
__global__ void k_post(const int* __restrict__ tok, const float* __restrict__ counts,
                       const float* __restrict__ dmin, const float* __restrict__ ea,
                       const float* __restrict__ cs, const float* __restrict__ scal,
                       const float* __restrict__ w, float* __restrict__ embed_sum,
                       float* __restrict__ o_cluster, float* __restrict__ o_wnew,
                       float* __restrict__ out) {
    __shared__ float t[32][33];
    __shared__ int tk[32];
    int blk = blockIdx.x;
    int tid = threadIdx.x;
    if (blk < 4096) {
        int k = blk * 4 + (tid >> 6);
        int lane = tid & 63;
        float4 sm4 = ((const float4*)(embed_sum + (size_t)k * DIM))[lane];
        float4 eav = ((const float4*)(ea + (size_t)k * DIM))[lane];
        float4 em = make_float4(DECAYF * eav.x + ONE_M_DECAY * sm4.x,
                                DECAYF * eav.y + ONE_M_DECAY * sm4.y,
                                DECAYF * eav.z + ONE_M_DECAY * sm4.z,
                                DECAYF * eav.w + ONE_M_DECAY * sm4.w);
        ((float4*)(embed_sum + (size_t)k * DIM))[lane] = em;   // o_embed in place
        float cn = DECAYF * cs[k] + ONE_M_DECAY * counts[k];
        float ntot = DECAYF * scal[1] + ONE_M_DECAY * (float)N_TOK;
        float smv = (cn + EPSF) / (ntot + (float)KCB * EPSF) * ntot;
        float inv = 1.0f / smv;
        ((float4*)(o_wnew + (size_t)k * DIM))[lane] =
            make_float4(em.x * inv, em.y * inv, em.z * inv, em.w * inv);
        if (lane == 0) o_cluster[k] = cn;
    } else if (blk < 8192) {
        int b2 = blk - 4096;
        int b = b2 >> 8, c0 = ((b2 >> 5) & 7) * 32, h0 = (b2 & 31) * 32;
        int jx = tid & 31, iy = tid >> 5;
        if (tid < 32) tk[tid] = tok[b * HW + h0 + tid];
        __syncthreads();
        #pragma unroll
        for (int p = 0; p < 4; ++p) {
            int hh = iy + p * 8;
            t[hh][jx] = w[(size_t)tk[hh] * DIM + c0 + jx];
        }
        __syncthreads();
        #pragma unroll
        for (int p = 0; p < 4; ++p) {
            int cc = iy + p * 8;
            out[(size_t)b * DIM * HW + (size_t)(c0 + cc) * HW + h0 + jx] = t[jx][cc];
        }
    } else {
        int k = (blk - 8192) * 256 + tid;
        int lane = tid & 63;
        float cnt = counts[k];
        float used = cnt > 0.f ? 1.f : 0.f;
        float p = cnt * (1.0f / 16384.0f);
        float pl = p * logf(p + 1e-10f);
        float dv = dmin[k];
        used = wave_reduce_sum(used);
        pl   = wave_reduce_sum(pl);
        dv   = wave_reduce_sum(dv);
        if (lane == 0) {
            atomicAdd((float*)&scal[2], used);
            atomicAdd((float*)&scal[3], pl);
            atomicAdd((float*)&scal[0], dv);
        }
    }
}

// ---- K10: scalar outputs ----
__global__ void k_scalars(const float* __restrict__ scal, float* __restrict__ o_scal) {
    if (threadIdx.x == 0) {
        float sumsq = scal[0], used = scal[2], plogp = scal[3];
        o_scal[0] = BETAF * sumsq / (float)(N_TOK * DIM);
        o_scal[1] = sumsq / (float)N_TOK;
        o_scal[2] = used * (1.0f / (float)KCB);
        o_scal[3] = expf(-plogp);
    }
}

extern "C" void kernel_launch(void* const* d_in, const int* in_sizes, int n_in,
                              void* d_out, int out_size, void* d_ws, size_t ws_size,
                              hipStream_t stream) {
    const float* z  = (const float*)d_in[0];
    const float* w  = (const float*)d_in[1];
    const float* cs = (const float*)d_in[2];
    const float* ea = (const float*)d_in[3];
    float* out = (float*)d_out;

    char* w8 = (char*)d_ws;
    unsigned short* Ah = (unsigned short*)(w8 + 0);          //  8 MB
    unsigned short* Bh = (unsigned short*)(w8 + 8388608);    //  8 MB
    int*   tok     = (int*)(w8 + 16777216);                  // 64 KB
    float* counts  = (float*)(w8 + 16842752);                // 64 KB (zeroed)
    float* dmin    = (float*)(w8 + 16908288);                // 64 KB
    float* scal    = (float*)(w8 + 16973824);                // 64 B (zeroed)

    // aliased into d_out:
    float* zf = out;                                   // [0,16MB): overwritten by k_post write_out
    uint2* pout = (uint2*)(out + 4194308);             // 1 MB inside o_wnew; consumed by k_select
    float* o_scal    = out + 4194304;
    float* o_wnew    = out + 4194308;
    float* o_cluster = out + 8388612;
    float* o_embed   = out + 8404996;                  // doubles as embed_sum accumulator

    hipMemsetAsync(counts, 0, 16973824 + 64 - 16842752, stream);       // counts..scal
    hipMemsetAsync(o_embed, 0, (size_t)N_TOK * DIM * 4, stream);       // embed_sum = 0
    k_pre<<<8256, 256, 0, stream>>>(z, zf, Ah, w, Bh, cs, scal);
    k_gemm_argmin<<<dim3(128, STRIPS), 256, 0, stream>>>(Ah, Bh, pout);
    k_select<<<4096, 256, 0, stream>>>(pout, zf, w, tok, counts, dmin, o_embed);
    k_post<<<8256, 256, 0, stream>>>(tok, counts, dmin, ea, cs, scal, w,
                                     o_embed, o_cluster, o_wnew, out);
    k_scalars<<<1, 64, 0, stream>>>(scal, o_scal);
}

// Round 11
// 309.720 us; speedup vs baseline: 1.1059x; 1.1059x over previous
//
#include <hip/hip_runtime.h>

#define N_TOK 16384
#define KCB   16384
#define DIM   256
#define HW    1024
#define DECAYF 0.8f
#define ONE_M_DECAY 0.2f
#define BETAF 0.25f
#define EPSF  1e-5f
#define STRIPS 8
#define KB_PER 16

typedef __attribute__((ext_vector_type(8))) short bf16x8;
typedef __attribute__((ext_vector_type(4))) float f32x4;

__device__ __forceinline__ float wave_reduce_sum(float s) {
    #pragma unroll
    for (int o = 32; o > 0; o >>= 1) s += __shfl_down(s, o);
    return s;
}

__device__ __forceinline__ unsigned short f2bf(float x) {
    union { float f; unsigned int u; } a; a.f = x;
    unsigned int r = a.u + 0x7fffu + ((a.u >> 16) & 1u);
    return (unsigned short)(r >> 16);
}

// ---- K_pre: fused {transpose z -> zf/Ah} + {Bh = bf16(w)} + {sum(cs)} ----
__global__ void k_pre(const float* __restrict__ z, float* __restrict__ zf,
                      unsigned short* __restrict__ Ah, const float* __restrict__ w,
                      unsigned short* __restrict__ Bh, const float* __restrict__ cs,
                      float* __restrict__ scal) {
    __shared__ float t[32][33];
    int blk = blockIdx.x;
    int tid = threadIdx.x;
    if (blk < 4096) {
        int b = blk >> 8, c0 = ((blk >> 5) & 7) * 32, h0 = (blk & 31) * 32;
        int jx = tid & 31, iy = tid >> 5;
        const float* zb = z + (size_t)b * DIM * HW;
        #pragma unroll
        for (int p = 0; p < 4; ++p) {
            int ci = iy + p * 8;
            t[ci][jx] = zb[(size_t)(c0 + ci) * HW + h0 + jx];
        }
        __syncthreads();
        #pragma unroll
        for (int p = 0; p < 4; ++p) {
            int hh = iy + p * 8;
            size_t idx = (size_t)(b * HW + h0 + hh) * DIM + c0 + jx;
            float v = t[jx][hh];
            zf[idx] = v;
            Ah[idx] = f2bf(v);
        }
    } else if (blk < 8192) {
        int wv = (blk - 4096) * 4 + (tid >> 6);
        int lane = tid & 63;
        float4 v = ((const float4*)(w + (size_t)wv * DIM))[lane];
        ushort4 h;
        h.x = f2bf(v.x); h.y = f2bf(v.y); h.z = f2bf(v.z); h.w = f2bf(v.w);
        ((ushort4*)(Bh + (size_t)wv * DIM))[lane] = h;
    } else {
        int i = (blk - 8192) * 256 + tid;
        int lane = tid & 63;
        float v = cs[i];
        v = wave_reduce_sum(v);
        if (lane == 0) atomicAdd(&scal[1], v);
    }
}

// ---- K3: bf16 MFMA GEMM (wnorm-free). m201 phase order:
// ----     ds_read -> stage-issue -> barrier -> MFMA cluster -> vmcnt(0) -> barrier ----
__global__ __launch_bounds__(256, 2) void k_gemm_argmin(
    const unsigned short* __restrict__ Ah, const unsigned short* __restrict__ Bh,
    uint2* __restrict__ pout) {
    __shared__ unsigned short As[128 * 256];   // 64 KB, 16B-chunk pos = c ^ (row&7)
    __shared__ unsigned short Bs[2][128 * 32]; // 2 x 8 KB, 16B-chunk pos = c ^ (row&3)

    int tid  = threadIdx.x;
    int wave = tid >> 6, lane = tid & 63;
    int g16  = lane >> 4, r16 = lane & 15;
    int n0   = blockIdx.x * 128;
    int strip = blockIdx.y;

    #pragma unroll
    for (int i = 0; i < 16; ++i) {
        int s = (wave * 16 + i) * 64 + lane;
        int row = s >> 5, pos = s & 31;
        int c = pos ^ (row & 7);
        const unsigned int* ga = (const unsigned int*)(Ah + (size_t)(n0 + row) * 256 + c * 8);
        unsigned int* la = (unsigned int*)&As[(size_t)((wave * 16 + i) * 64) * 8];
        __builtin_amdgcn_global_load_lds((const __attribute__((address_space(1))) unsigned int*)ga,
                                         (__attribute__((address_space(3))) unsigned int*)la, 16, 0, 0);
    }

    auto stageB = [&](int kb, int ks, int buf) {
        int c0 = (strip * KB_PER + kb) * 128;
        #pragma unroll
        for (int j = 0; j < 2; ++j) {
            int s = (wave * 2 + j) * 64 + lane;
            int m = s >> 2, pk = (s & 3) ^ (m & 3);
            const unsigned int* gb = (const unsigned int*)(Bh + (size_t)(c0 + m) * 256 + ks * 32 + pk * 8);
            unsigned int* lb = (unsigned int*)&Bs[buf][(size_t)((wave * 2 + j) * 64) * 8];
            __builtin_amdgcn_global_load_lds((const __attribute__((address_space(1))) unsigned int*)gb,
                                             (__attribute__((address_space(3))) unsigned int*)lb, 16, 0, 0);
        }
    };

    stageB(0, 0, 0);

    asm volatile("s_waitcnt vmcnt(0)" ::: "memory");
    __builtin_amdgcn_s_barrier();
    asm volatile("" ::: "memory");

    unsigned int b1[16], b2[16];
    #pragma unroll
    for (int i = 0; i < 16; ++i) { b1[i] = 0xFFFFFFFFu; b2[i] = 0xFFFFFFFFu; }

    for (int kbi = 0; kbi < KB_PER; ++kbi) {
        f32x4 acc[4][4];
        #pragma unroll
        for (int mt = 0; mt < 4; ++mt)
            #pragma unroll
            for (int nt = 0; nt < 4; ++nt)
                acc[mt][nt] = (f32x4){0.f, 0.f, 0.f, 0.f};

        #pragma unroll
        for (int ks = 0; ks < 8; ++ks) {
            bf16x8 af[4], bfr[4];
            #pragma unroll
            for (int mt = 0; mt < 4; ++mt) {
                int row = (wave >> 1) * 64 + mt * 16 + r16;
                int pos = (ks * 4 + g16) ^ (row & 7);
                af[mt] = *(const bf16x8*)&As[(row * 32 + pos) * 8];
            }
            #pragma unroll
            for (int nt = 0; nt < 4; ++nt) {
                int row = (wave & 1) * 64 + nt * 16 + r16;
                int pk = g16 ^ (row & 3);
                bfr[nt] = *(const bf16x8*)&Bs[ks & 1][(row * 4 + pk) * 8];
            }
            if (!(kbi == KB_PER - 1 && ks == 7)) {
                int nk = (ks == 7) ? kbi + 1 : kbi;
                stageB(nk, (ks + 1) & 7, (ks + 1) & 1);
            }
            __builtin_amdgcn_s_barrier();
            __builtin_amdgcn_sched_barrier(0);
            __builtin_amdgcn_s_setprio(1);
            #pragma unroll
            for (int mt = 0; mt < 4; ++mt)
                #pragma unroll
                for (int nt = 0; nt < 4; ++nt)
                    acc[mt][nt] = __builtin_amdgcn_mfma_f32_16x16x32_bf16(af[mt], bfr[nt], acc[mt][nt], 0, 0, 0);
            __builtin_amdgcn_s_setprio(0);
            asm volatile("s_waitcnt vmcnt(0)" ::: "memory");
            __builtin_amdgcn_s_barrier();
            asm volatile("" ::: "memory");
        }

        unsigned int orv[4];
        #pragma unroll
        for (int nt = 0; nt < 4; ++nt)
            orv[nt] = (unsigned int)((kbi << 7) | ((wave & 1) << 6) | (nt << 4));
        #pragma unroll
        for (int mt = 0; mt < 4; ++mt)
            #pragma unroll
            for (int rg = 0; rg < 4; ++rg) {
                int i = mt * 4 + rg;
                #pragma unroll
                for (int nt = 0; nt < 4; ++nt) {
                    float s = fmaf(-2.0f, acc[mt][nt][rg], 0.0625f);
                    unsigned int u = (__float_as_uint(s) & 0xFFFFF800u) | orv[nt];
                    unsigned int t2 = b1[i] > u ? b1[i] : u;
                    b1[i] = b1[i] < u ? b1[i] : u;
                    b2[i] = b2[i] < t2 ? b2[i] : t2;
                }
            }
    }

    #pragma unroll
    for (int i = 0; i < 16; ++i) {
        unsigned int v1 = b1[i] | (unsigned int)r16;
        unsigned int v2 = b2[i] | (unsigned int)r16;
        #pragma unroll
        for (int off = 1; off < 16; off <<= 1) {
            unsigned int o1 = __shfl_xor((int)v1, off);
            unsigned int o2 = __shfl_xor((int)v2, off);
            unsigned int n1 = v1 < o1 ? v1 : o1;
            unsigned int hi = v1 < o1 ? o1 : v1;
            unsigned int lo = v2 < o2 ? v2 : o2;
            v1 = n1;
            v2 = hi < lo ? hi : lo;
        }
        b1[i] = v1; b2[i] = v2;
    }

    __syncthreads();
    unsigned int* red1 = (unsigned int*)Bs;
    unsigned int* red2 = red1 + 256;
    if (r16 == 0) {
        #pragma unroll
        for (int mt = 0; mt < 4; ++mt)
            #pragma unroll
            for (int rg = 0; rg < 4; ++rg) {
                int row = (wave >> 1) * 64 + mt * 16 + g16 * 4 + rg;
                red1[(wave & 1) * 128 + row] = b1[mt * 4 + rg];
                red2[(wave & 1) * 128 + row] = b2[mt * 4 + rg];
            }
    }
    __syncthreads();
    if (tid < 128) {
        unsigned int a1 = red1[tid], a2 = red2[tid];
        unsigned int c1 = red1[128 + tid], c2 = red2[128 + tid];
        unsigned int m1 = a1 < c1 ? a1 : c1;
        unsigned int hi = a1 < c1 ? c1 : a1;
        unsigned int lo = a2 < c2 ? a2 : c2;
        pout[(size_t)strip * N_TOK + n0 + tid] = make_uint2(m1, hi < lo ? hi : lo);
    }
}

// ---- K4: merge strips + exact rescore -> (token, rank), dmin[n]; counts++ ----
__global__ void k_select(const uint2* __restrict__ pout, const float* __restrict__ zf,
                         const float* __restrict__ w, int2* __restrict__ tokrank,
                         float* __restrict__ counts, float* __restrict__ dmin) {
    int n = blockIdx.x * 4 + (threadIdx.x >> 6);
    int lane = threadIdx.x & 63;
    unsigned int c1 = 0xFFFFFFFFu, c2 = 0xFFFFFFFFu;
    int s1 = 0, s2 = 0;
    #pragma unroll
    for (int s = 0; s < STRIPS; ++s) {
        uint2 p = pout[(size_t)s * N_TOK + n];
        if (p.x < c1)      { c2 = c1; s2 = s1; c1 = p.x; s1 = s; }
        else if (p.x < c2) { c2 = p.x; s2 = s; }
        if (p.y < c1)      { c2 = c1; s2 = s1; c1 = p.y; s1 = s; }
        else if (p.y < c2) { c2 = p.y; s2 = s; }
    }
    int code1 = (s1 << 11) | (int)(c1 & 0x7FFu);
    int code2 = (s2 << 11) | (int)(c2 & 0x7FFu);

    float4 zv = ((const float4*)(zf + (size_t)n * DIM))[lane];
    float4 w1 = ((const float4*)(w + (size_t)code1 * DIM))[lane];
    float4 w2 = ((const float4*)(w + (size_t)code2 * DIM))[lane];
    float ax = zv.x - w1.x, ay = zv.y - w1.y, az = zv.z - w1.z, aw = zv.w - w1.w;
    float bx = zv.x - w2.x, by = zv.y - w2.y, bz = zv.z - w2.z, bw = zv.w - w2.w;
    float d1 = ax * ax + ay * ay + az * az + aw * aw;
    float d2 = bx * bx + by * by + bz * bz + bw * bw;
    d1 = wave_reduce_sum(d1);
    d2 = wave_reduce_sum(d2);
    if (lane == 0) {
        bool take2 = (d2 < d1) || (d2 == d1 && code2 < code1);
        int tok = take2 ? code2 : code1;
        dmin[n] = take2 ? d2 : d1;
        float old = atomicAdd(&counts[tok], 1.0f);
        tokrank[n] = make_int2(tok, (int)old);
    }
}

// ---- K5: single-block exclusive prefix sum of counts -> offsets ----
__global__ void k_scan(const float* __restrict__ counts, int* __restrict__ offsets) {
    int tid = threadIdx.x;                 // 256 threads, 64 codes each
    int lane = tid & 63, wv = tid >> 6;
    int base = tid * 64;
    int sum = 0;
    for (int i = 0; i < 64; ++i) sum += (int)counts[base + i];
    int x = sum;
    #pragma unroll
    for (int o = 1; o < 64; o <<= 1) {
        int y = __shfl_up(x, o);
        if (lane >= o) x += y;
    }
    __shared__ int wt[4];
    if (lane == 63) wt[wv] = x;
    __syncthreads();
    int wbase = 0;
    for (int i = 0; i < wv; ++i) wbase += wt[i];
    int run = wbase + x - sum;             // exclusive base for this thread's chunk
    for (int i = 0; i < 64; ++i) {
        offsets[base + i] = run;
        run += (int)counts[base + i];
    }
}

// ---- K6: perm[offsets[tok] + rank] = n ----
__global__ void k_scatter(const int2* __restrict__ tokrank, const int* __restrict__ offsets,
                          int* __restrict__ perm) {
    int n = blockIdx.x * 256 + threadIdx.x;
    int2 tr = tokrank[n];
    perm[offsets[tr.x] + tr.y] = n;
}

// ---- K7: one wave per code: gather z rows, emit embed_avg_new/cluster_new/weight_new ----
__global__ void k_embed(const int* __restrict__ offsets, const float* __restrict__ counts,
                        const int* __restrict__ perm, const float* __restrict__ zf,
                        const float* __restrict__ ea, const float* __restrict__ cs,
                        const float* __restrict__ scal, float* __restrict__ o_embed,
                        float* __restrict__ o_cluster, float* __restrict__ o_wnew) {
    int k = blockIdx.x * 4 + (threadIdx.x >> 6);
    int lane = threadIdx.x & 63;
    int off = offsets[k];
    int c = (int)counts[k];
    float4 acc = make_float4(0.f, 0.f, 0.f, 0.f);
    for (int i = 0; i < c; ++i) {
        int n = perm[off + i];
        float4 zv = ((const float4*)(zf + (size_t)n * DIM))[lane];
        acc.x += zv.x; acc.y += zv.y; acc.z += zv.z; acc.w += zv.w;
    }
    float4 eav = ((const float4*)(ea + (size_t)k * DIM))[lane];
    float4 em = make_float4(DECAYF * eav.x + ONE_M_DECAY * acc.x,
                            DECAYF * eav.y + ONE_M_DECAY * acc.y,
                            DECAYF * eav.z + ONE_M_DECAY * acc.z,
                            DECAYF * eav.w + ONE_M_DECAY * acc.w);
    ((float4*)(o_embed + (size_t)k * DIM))[lane] = em;
    float cn = DECAYF * cs[k] + ONE_M_DECAY * (float)c;
    float ntot = DECAYF * scal[1] + ONE_M_DECAY * (float)N_TOK;  // sum(cluster_new) analytic
    float sm = (cn + EPSF) / (ntot + (float)KCB * EPSF) * ntot;
    float inv = 1.0f / sm;
    ((float4*)(o_wnew + (size_t)k * DIM))[lane] =
        make_float4(em.x * inv, em.y * inv, em.z * inv, em.w * inv);
    if (lane == 0) o_cluster[k] = cn;
}

// ---- K_post2: fused {write_out} + {stats} ----
__global__ void k_post2(const int2* __restrict__ tokrank, const float* __restrict__ w,
                        const float* __restrict__ counts, const float* __restrict__ dmin,
                        float* __restrict__ scal, float* __restrict__ out) {
    __shared__ float t[32][33];
    __shared__ int tk[32];
    int blk = blockIdx.x;
    int tid = threadIdx.x;
    if (blk < 4096) {
        int b = blk >> 8, c0 = ((blk >> 5) & 7) * 32, h0 = (blk & 31) * 32;
        int jx = tid & 31, iy = tid >> 5;
        if (tid < 32) tk[tid] = tokrank[b * HW + h0 + tid].x;
        __syncthreads();
        #pragma unroll
        for (int p = 0; p < 4; ++p) {
            int hh = iy + p * 8;
            t[hh][jx] = w[(size_t)tk[hh] * DIM + c0 + jx];
        }
        __syncthreads();
        #pragma unroll
        for (int p = 0; p < 4; ++p) {
            int cc = iy + p * 8;
            out[(size_t)b * DIM * HW + (size_t)(c0 + cc) * HW + h0 + jx] = t[jx][cc];
        }
    } else {
        int k = (blk - 4096) * 256 + tid;
        int lane = tid & 63;
        float cnt = counts[k];
        float used = cnt > 0.f ? 1.f : 0.f;
        float p = cnt * (1.0f / 16384.0f);
        float pl = p * logf(p + 1e-10f);
        float dv = dmin[k];
        used = wave_reduce_sum(used);
        pl   = wave_reduce_sum(pl);
        dv   = wave_reduce_sum(dv);
        if (lane == 0) {
            atomicAdd(&scal[2], used);
            atomicAdd(&scal[3], pl);
            atomicAdd(&scal[0], dv);
        }
    }
}

// ---- K10: scalar outputs ----
__global__ void k_scalars(const float* __restrict__ scal, float* __restrict__ o_scal) {
    if (threadIdx.x == 0) {
        float sumsq = scal[0], used = scal[2], plogp = scal[3];
        o_scal[0] = BETAF * sumsq / (float)(N_TOK * DIM);
        o_scal[1] = sumsq / (float)N_TOK;
        o_scal[2] = used * (1.0f / (float)KCB);
        o_scal[3] = expf(-plogp);
    }
}

extern "C" void kernel_launch(void* const* d_in, const int* in_sizes, int n_in,
                              void* d_out, int out_size, void* d_ws, size_t ws_size,
                              hipStream_t stream) {
    const float* z  = (const float*)d_in[0];
    const float* w  = (const float*)d_in[1];
    const float* cs = (const float*)d_in[2];
    const float* ea = (const float*)d_in[3];
    float* out = (float*)d_out;

    char* w8 = (char*)d_ws;
    unsigned short* Ah = (unsigned short*)(w8 + 0);          //  8 MB
    unsigned short* Bh = (unsigned short*)(w8 + 8388608);    //  8 MB
    int2*  tokrank = (int2*)(w8 + 16777216);                 // 128 KB
    float* counts  = (float*)(w8 + 16908288);                // 64 KB (zeroed)
    int*   offsets = (int*)(w8 + 16973824);                  // 64 KB
    int*   perm    = (int*)(w8 + 17039360);                  // 64 KB
    float* dmin    = (float*)(w8 + 17104896);                // 64 KB
    float* scal    = (float*)(w8 + 17170432);                // 64 B (zeroed)

    // aliased into d_out:
    float* zf = out;                                   // [0,16MB): overwritten by k_post2 write_out
    uint2* pout = (uint2*)(out + 4194308);             // 1 MB inside o_wnew; consumed by k_select
    float* o_scal    = out + 4194304;
    float* o_wnew    = out + 4194308;
    float* o_cluster = out + 8388612;
    float* o_embed   = out + 8404996;

    hipMemsetAsync(counts, 0, 17170432 + 64 - 16908288, stream);  // counts..scal
    k_pre<<<8256, 256, 0, stream>>>(z, zf, Ah, w, Bh, cs, scal);
    k_gemm_argmin<<<dim3(128, STRIPS), 256, 0, stream>>>(Ah, Bh, pout);
    k_select<<<4096, 256, 0, stream>>>(pout, zf, w, tokrank, counts, dmin);
    k_scan<<<1, 256, 0, stream>>>(counts, offsets);
    k_scatter<<<64, 256, 0, stream>>>(tokrank, offsets, perm);
    k_embed<<<4096, 256, 0, stream>>>(offsets, counts, perm, zf, ea, cs, scal,
                                      o_embed, o_cluster, o_wnew);
    k_post2<<<4160, 256, 0, stream>>>(tokrank, w, counts, dmin, scal, out);
    k_scalars<<<1, 64, 0, stream>>>(scal, o_scal);
}

// Round 12
// 301.886 us; speedup vs baseline: 1.1346x; 1.0260x over previous
//
#include <hip/hip_runtime.h>

#define N_TOK 16384
#define KCB   16384
#define DIM   256
#define HW    1024
#define DECAYF 0.8f
#define ONE_M_DECAY 0.2f
#define BETAF 0.25f
#define EPSF  1e-5f
#define STRIPS 8
#define KB_PER 16

typedef __attribute__((ext_vector_type(8))) short bf16x8;
typedef __attribute__((ext_vector_type(4))) float f32x4;

__device__ __forceinline__ float wave_reduce_sum(float s) {
    #pragma unroll
    for (int o = 32; o > 0; o >>= 1) s += __shfl_down(s, o);
    return s;
}

__device__ __forceinline__ unsigned short f2bf(float x) {
    union { float f; unsigned int u; } a; a.f = x;
    unsigned int r = a.u + 0x7fffu + ((a.u >> 16) & 1u);
    return (unsigned short)(r >> 16);
}

// ---- K_pre: fused {float4 transpose z -> zf/Ah (32c x 128h tiles)} +
// ----        {Bh = bf16(w)} + {sum(cs)} + {counts = 0} ----
__global__ void k_pre(const float* __restrict__ z, float* __restrict__ zf,
                      unsigned short* __restrict__ Ah, const float* __restrict__ w,
                      unsigned short* __restrict__ Bh, const float* __restrict__ cs,
                      float* __restrict__ scal, float* __restrict__ counts) {
    __shared__ float t[128][33];
    int blk = blockIdx.x;
    int tid = threadIdx.x;
    if (blk < 1024) {
        // transpose: b = blk>>6, c-tile = (blk>>3)&7, h-tile = blk&7 (128 wide)
        int b = blk >> 6, c0 = ((blk >> 3) & 7) * 32, h0 = (blk & 7) * 128;
        int ci = tid >> 3, jx = tid & 7;
        const float* zb = z + (size_t)b * DIM * HW;
        #pragma unroll
        for (int hs = 0; hs < 4; ++hs) {
            float4 v = *(const float4*)&zb[(size_t)(c0 + ci) * HW + h0 + hs * 32 + jx * 4];
            int hl = hs * 32 + jx * 4;
            t[hl + 0][ci] = v.x; t[hl + 1][ci] = v.y;
            t[hl + 2][ci] = v.z; t[hl + 3][ci] = v.w;
        }
        __syncthreads();
        int hr = tid >> 3, m = tid & 7;
        #pragma unroll
        for (int ps = 0; ps < 4; ++ps) {
            int hl = ps * 32 + hr;
            float4 v = make_float4(t[hl][4 * m], t[hl][4 * m + 1],
                                   t[hl][4 * m + 2], t[hl][4 * m + 3]);
            size_t idx = (size_t)(b * HW + h0 + hl) * DIM + c0 + 4 * m;
            *(float4*)&zf[idx] = v;
            ushort4 hh;
            hh.x = f2bf(v.x); hh.y = f2bf(v.y); hh.z = f2bf(v.z); hh.w = f2bf(v.w);
            *(ushort4*)&Ah[idx] = hh;
        }
    } else if (blk < 5120) {
        int wv = (blk - 1024) * 4 + (tid >> 6);
        int lane = tid & 63;
        float4 v = ((const float4*)(w + (size_t)wv * DIM))[lane];
        ushort4 h;
        h.x = f2bf(v.x); h.y = f2bf(v.y); h.z = f2bf(v.z); h.w = f2bf(v.w);
        ((ushort4*)(Bh + (size_t)wv * DIM))[lane] = h;
    } else if (blk < 5184) {
        int i = (blk - 5120) * 256 + tid;
        int lane = tid & 63;
        float v = cs[i];
        v = wave_reduce_sum(v);
        if (lane == 0) atomicAdd(&scal[1], v);
    } else {
        counts[(blk - 5184) * 256 + tid] = 0.0f;
    }
}

// ---- K3: bf16 MFMA GEMM (wnorm-free). m201 phase order:
// ----     ds_read -> stage-issue -> barrier -> MFMA cluster -> vmcnt(0) -> barrier ----
__global__ __launch_bounds__(256, 2) void k_gemm_argmin(
    const unsigned short* __restrict__ Ah, const unsigned short* __restrict__ Bh,
    uint2* __restrict__ pout) {
    __shared__ unsigned short As[128 * 256];   // 64 KB, 16B-chunk pos = c ^ (row&7)
    __shared__ unsigned short Bs[2][128 * 32]; // 2 x 8 KB, 16B-chunk pos = c ^ (row&3)

    int tid  = threadIdx.x;
    int wave = tid >> 6, lane = tid & 63;
    int g16  = lane >> 4, r16 = lane & 15;
    int n0   = blockIdx.x * 128;
    int strip = blockIdx.y;

    #pragma unroll
    for (int i = 0; i < 16; ++i) {
        int s = (wave * 16 + i) * 64 + lane;
        int row = s >> 5, pos = s & 31;
        int c = pos ^ (row & 7);
        const unsigned int* ga = (const unsigned int*)(Ah + (size_t)(n0 + row) * 256 + c * 8);
        unsigned int* la = (unsigned int*)&As[(size_t)((wave * 16 + i) * 64) * 8];
        __builtin_amdgcn_global_load_lds((const __attribute__((address_space(1))) unsigned int*)ga,
                                         (__attribute__((address_space(3))) unsigned int*)la, 16, 0, 0);
    }

    auto stageB = [&](int kb, int ks, int buf) {
        int c0 = (strip * KB_PER + kb) * 128;
        #pragma unroll
        for (int j = 0; j < 2; ++j) {
            int s = (wave * 2 + j) * 64 + lane;
            int m = s >> 2, pk = (s & 3) ^ (m & 3);
            const unsigned int* gb = (const unsigned int*)(Bh + (size_t)(c0 + m) * 256 + ks * 32 + pk * 8);
            unsigned int* lb = (unsigned int*)&Bs[buf][(size_t)((wave * 2 + j) * 64) * 8];
            __builtin_amdgcn_global_load_lds((const __attribute__((address_space(1))) unsigned int*)gb,
                                             (__attribute__((address_space(3))) unsigned int*)lb, 16, 0, 0);
        }
    };

    stageB(0, 0, 0);

    asm volatile("s_waitcnt vmcnt(0)" ::: "memory");
    __builtin_amdgcn_s_barrier();
    asm volatile("" ::: "memory");

    unsigned int b1[16], b2[16];
    #pragma unroll
    for (int i = 0; i < 16; ++i) { b1[i] = 0xFFFFFFFFu; b2[i] = 0xFFFFFFFFu; }

    for (int kbi = 0; kbi < KB_PER; ++kbi) {
        f32x4 acc[4][4];
        #pragma unroll
        for (int mt = 0; mt < 4; ++mt)
            #pragma unroll
            for (int nt = 0; nt < 4; ++nt)
                acc[mt][nt] = (f32x4){0.f, 0.f, 0.f, 0.f};

        #pragma unroll
        for (int ks = 0; ks < 8; ++ks) {
            bf16x8 af[4], bfr[4];
            #pragma unroll
            for (int mt = 0; mt < 4; ++mt) {
                int row = (wave >> 1) * 64 + mt * 16 + r16;
                int pos = (ks * 4 + g16) ^ (row & 7);
                af[mt] = *(const bf16x8*)&As[(row * 32 + pos) * 8];
            }
            #pragma unroll
            for (int nt = 0; nt < 4; ++nt) {
                int row = (wave & 1) * 64 + nt * 16 + r16;
                int pk = g16 ^ (row & 3);
                bfr[nt] = *(const bf16x8*)&Bs[ks & 1][(row * 4 + pk) * 8];
            }
            if (!(kbi == KB_PER - 1 && ks == 7)) {
                int nk = (ks == 7) ? kbi + 1 : kbi;
                stageB(nk, (ks + 1) & 7, (ks + 1) & 1);
            }
            __builtin_amdgcn_s_barrier();
            __builtin_amdgcn_sched_barrier(0);
            __builtin_amdgcn_s_setprio(1);
            #pragma unroll
            for (int mt = 0; mt < 4; ++mt)
                #pragma unroll
                for (int nt = 0; nt < 4; ++nt)
                    acc[mt][nt] = __builtin_amdgcn_mfma_f32_16x16x32_bf16(af[mt], bfr[nt], acc[mt][nt], 0, 0, 0);
            __builtin_amdgcn_s_setprio(0);
            asm volatile("s_waitcnt vmcnt(0)" ::: "memory");
            __builtin_amdgcn_s_barrier();
            asm volatile("" ::: "memory");
        }

        unsigned int orv[4];
        #pragma unroll
        for (int nt = 0; nt < 4; ++nt)
            orv[nt] = (unsigned int)((kbi << 7) | ((wave & 1) << 6) | (nt << 4));
        #pragma unroll
        for (int mt = 0; mt < 4; ++mt)
            #pragma unroll
            for (int rg = 0; rg < 4; ++rg) {
                int i = mt * 4 + rg;
                #pragma unroll
                for (int nt = 0; nt < 4; ++nt) {
                    float s = fmaf(-2.0f, acc[mt][nt][rg], 0.0625f);
                    unsigned int u = (__float_as_uint(s) & 0xFFFFF800u) | orv[nt];
                    unsigned int t2 = b1[i] > u ? b1[i] : u;
                    b1[i] = b1[i] < u ? b1[i] : u;
                    b2[i] = b2[i] < t2 ? b2[i] : t2;
                }
            }
    }

    #pragma unroll
    for (int i = 0; i < 16; ++i) {
        unsigned int v1 = b1[i] | (unsigned int)r16;
        unsigned int v2 = b2[i] | (unsigned int)r16;
        #pragma unroll
        for (int off = 1; off < 16; off <<= 1) {
            unsigned int o1 = __shfl_xor((int)v1, off);
            unsigned int o2 = __shfl_xor((int)v2, off);
            unsigned int n1 = v1 < o1 ? v1 : o1;
            unsigned int hi = v1 < o1 ? o1 : v1;
            unsigned int lo = v2 < o2 ? v2 : o2;
            v1 = n1;
            v2 = hi < lo ? hi : lo;
        }
        b1[i] = v1; b2[i] = v2;
    }

    __syncthreads();
    unsigned int* red1 = (unsigned int*)Bs;
    unsigned int* red2 = red1 + 256;
    if (r16 == 0) {
        #pragma unroll
        for (int mt = 0; mt < 4; ++mt)
            #pragma unroll
            for (int rg = 0; rg < 4; ++rg) {
                int row = (wave >> 1) * 64 + mt * 16 + g16 * 4 + rg;
                red1[(wave & 1) * 128 + row] = b1[mt * 4 + rg];
                red2[(wave & 1) * 128 + row] = b2[mt * 4 + rg];
            }
    }
    __syncthreads();
    if (tid < 128) {
        unsigned int a1 = red1[tid], a2 = red2[tid];
        unsigned int c1 = red1[128 + tid], c2 = red2[128 + tid];
        unsigned int m1 = a1 < c1 ? a1 : c1;
        unsigned int hi = a1 < c1 ? c1 : a1;
        unsigned int lo = a2 < c2 ? a2 : c2;
        pout[(size_t)strip * N_TOK + n0 + tid] = make_uint2(m1, hi < lo ? hi : lo);
    }
}

// ---- K4: merge strips + exact rescore -> (token, rank), dmin[n]; counts++ ----
__global__ void k_select(const uint2* __restrict__ pout, const float* __restrict__ zf,
                         const float* __restrict__ w, int2* __restrict__ tokrank,
                         float* __restrict__ counts, float* __restrict__ dmin) {
    int n = blockIdx.x * 4 + (threadIdx.x >> 6);
    int lane = threadIdx.x & 63;
    unsigned int c1 = 0xFFFFFFFFu, c2 = 0xFFFFFFFFu;
    int s1 = 0, s2 = 0;
    #pragma unroll
    for (int s = 0; s < STRIPS; ++s) {
        uint2 p = pout[(size_t)s * N_TOK + n];
        if (p.x < c1)      { c2 = c1; s2 = s1; c1 = p.x; s1 = s; }
        else if (p.x < c2) { c2 = p.x; s2 = s; }
        if (p.y < c1)      { c2 = c1; s2 = s1; c1 = p.y; s1 = s; }
        else if (p.y < c2) { c2 = p.y; s2 = s; }
    }
    int code1 = (s1 << 11) | (int)(c1 & 0x7FFu);
    int code2 = (s2 << 11) | (int)(c2 & 0x7FFu);

    float4 zv = ((const float4*)(zf + (size_t)n * DIM))[lane];
    float4 w1 = ((const float4*)(w + (size_t)code1 * DIM))[lane];
    float4 w2 = ((const float4*)(w + (size_t)code2 * DIM))[lane];
    float ax = zv.x - w1.x, ay = zv.y - w1.y, az = zv.z - w1.z, aw = zv.w - w1.w;
    float bx = zv.x - w2.x, by = zv.y - w2.y, bz = zv.z - w2.z, bw = zv.w - w2.w;
    float d1 = ax * ax + ay * ay + az * az + aw * aw;
    float d2 = bx * bx + by * by + bz * bz + bw * bw;
    d1 = wave_reduce_sum(d1);
    d2 = wave_reduce_sum(d2);
    if (lane == 0) {
        bool take2 = (d2 < d1) || (d2 == d1 && code2 < code1);
        int tok = take2 ? code2 : code1;
        dmin[n] = take2 ? d2 : d1;
        float old = atomicAdd(&counts[tok], 1.0f);
        tokrank[n] = make_int2(tok, (int)old);
    }
}

// ---- K5: single-block exclusive prefix sum of counts -> offsets ----
__global__ void k_scan(const float* __restrict__ counts, int* __restrict__ offsets) {
    int tid = threadIdx.x;                 // 256 threads, 64 codes each
    int lane = tid & 63, wv = tid >> 6;
    int base = tid * 64;
    int sum = 0;
    for (int i = 0; i < 64; ++i) sum += (int)counts[base + i];
    int x = sum;
    #pragma unroll
    for (int o = 1; o < 64; o <<= 1) {
        int y = __shfl_up(x, o);
        if (lane >= o) x += y;
    }
    __shared__ int wt[4];
    if (lane == 63) wt[wv] = x;
    __syncthreads();
    int wbase = 0;
    for (int i = 0; i < wv; ++i) wbase += wt[i];
    int run = wbase + x - sum;             // exclusive base for this thread's chunk
    for (int i = 0; i < 64; ++i) {
        offsets[base + i] = run;
        run += (int)counts[base + i];
    }
}

// ---- K6: perm[offsets[tok] + rank] = n ----
__global__ void k_scatter(const int2* __restrict__ tokrank, const int* __restrict__ offsets,
                          int* __restrict__ perm) {
    int n = blockIdx.x * 256 + threadIdx.x;
    int2 tr = tokrank[n];
    perm[offsets[tr.x] + tr.y] = n;
}

// ---- K7: one wave per code: gather z rows, emit embed_avg_new/cluster_new/weight_new ----
__global__ void k_embed(const int* __restrict__ offsets, const float* __restrict__ counts,
                        const int* __restrict__ perm, const float* __restrict__ zf,
                        const float* __restrict__ ea, const float* __restrict__ cs,
                        const float* __restrict__ scal, float* __restrict__ o_embed,
                        float* __restrict__ o_cluster, float* __restrict__ o_wnew) {
    int k = blockIdx.x * 4 + (threadIdx.x >> 6);
    int lane = threadIdx.x & 63;
    int off = offsets[k];
    int c = (int)counts[k];
    float4 acc = make_float4(0.f, 0.f, 0.f, 0.f);
    for (int i = 0; i < c; ++i) {
        int n = perm[off + i];
        float4 zv = ((const float4*)(zf + (size_t)n * DIM))[lane];
        acc.x += zv.x; acc.y += zv.y; acc.z += zv.z; acc.w += zv.w;
    }
    float4 eav = ((const float4*)(ea + (size_t)k * DIM))[lane];
    float4 em = make_float4(DECAYF * eav.x + ONE_M_DECAY * acc.x,
                            DECAYF * eav.y + ONE_M_DECAY * acc.y,
                            DECAYF * eav.z + ONE_M_DECAY * acc.z,
                            DECAYF * eav.w + ONE_M_DECAY * acc.w);
    ((float4*)(o_embed + (size_t)k * DIM))[lane] = em;
    float cn = DECAYF * cs[k] + ONE_M_DECAY * (float)c;
    float ntot = DECAYF * scal[1] + ONE_M_DECAY * (float)N_TOK;  // sum(cluster_new) analytic
    float sm = (cn + EPSF) / (ntot + (float)KCB * EPSF) * ntot;
    float inv = 1.0f / sm;
    ((float4*)(o_wnew + (size_t)k * DIM))[lane] =
        make_float4(em.x * inv, em.y * inv, em.z * inv, em.w * inv);
    if (lane == 0) o_cluster[k] = cn;
}

// ---- K_post2: fused {float4 write_out (32c x 128h tiles)} + {stats} ----
__global__ void k_post2(const int2* __restrict__ tokrank, const float* __restrict__ w,
                        const float* __restrict__ counts, const float* __restrict__ dmin,
                        float* __restrict__ scal, float* __restrict__ out) {
    __shared__ float t[32][133];
    __shared__ int tk[128];
    int blk = blockIdx.x;
    int tid = threadIdx.x;
    if (blk < 1024) {
        int b = blk >> 6, c0 = ((blk >> 3) & 7) * 32, h0 = (blk & 7) * 128;
        if (tid < 128) tk[tid] = tokrank[b * HW + h0 + tid].x;
        __syncthreads();
        int hr = tid >> 3, m = tid & 7;
        #pragma unroll
        for (int ps = 0; ps < 4; ++ps) {
            int hl = ps * 32 + hr;
            float4 wv = *(const float4*)&w[(size_t)tk[hl] * DIM + c0 + 4 * m];
            t[4 * m + 0][hl] = wv.x; t[4 * m + 1][hl] = wv.y;
            t[4 * m + 2][hl] = wv.z; t[4 * m + 3][hl] = wv.w;
        }
        __syncthreads();
        int cc = tid >> 3;
        #pragma unroll
        for (int hs = 0; hs < 4; ++hs) {
            int hb = hs * 32 + 4 * m;
            float4 v = make_float4(t[cc][hb], t[cc][hb + 1], t[cc][hb + 2], t[cc][hb + 3]);
            *(float4*)&out[((size_t)b * DIM + c0 + cc) * HW + h0 + hb] = v;
        }
    } else {
        int k = (blk - 1024) * 256 + tid;
        int lane = tid & 63;
        float cnt = counts[k];
        float used = cnt > 0.f ? 1.f : 0.f;
        float p = cnt * (1.0f / 16384.0f);
        float pl = p * logf(p + 1e-10f);
        float dv = dmin[k];
        used = wave_reduce_sum(used);
        pl   = wave_reduce_sum(pl);
        dv   = wave_reduce_sum(dv);
        if (lane == 0) {
            atomicAdd(&scal[2], used);
            atomicAdd(&scal[3], pl);
            atomicAdd(&scal[0], dv);
        }
    }
}

// ---- K10: scalar outputs ----
__global__ void k_scalars(const float* __restrict__ scal, float* __restrict__ o_scal) {
    if (threadIdx.x == 0) {
        float sumsq = scal[0], used = scal[2], plogp = scal[3];
        o_scal[0] = BETAF * sumsq / (float)(N_TOK * DIM);
        o_scal[1] = sumsq / (float)N_TOK;
        o_scal[2] = used * (1.0f / (float)KCB);
        o_scal[3] = expf(-plogp);
    }
}

extern "C" void kernel_launch(void* const* d_in, const int* in_sizes, int n_in,
                              void* d_out, int out_size, void* d_ws, size_t ws_size,
                              hipStream_t stream) {
    const float* z  = (const float*)d_in[0];
    const float* w  = (const float*)d_in[1];
    const float* cs = (const float*)d_in[2];
    const float* ea = (const float*)d_in[3];
    float* out = (float*)d_out;

    char* w8 = (char*)d_ws;
    unsigned short* Ah = (unsigned short*)(w8 + 0);          //  8 MB
    unsigned short* Bh = (unsigned short*)(w8 + 8388608);    //  8 MB
    int2*  tokrank = (int2*)(w8 + 16777216);                 // 128 KB
    float* counts  = (float*)(w8 + 16908288);                // 64 KB (zeroed in k_pre)
    int*   offsets = (int*)(w8 + 16973824);                  // 64 KB
    int*   perm    = (int*)(w8 + 17039360);                  // 64 KB
    float* dmin    = (float*)(w8 + 17104896);                // 64 KB
    float* scal    = (float*)(w8 + 17170432);                // 64 B (zeroed)

    // aliased into d_out:
    float* zf = out;                                   // [0,16MB): overwritten by k_post2 write_out
    uint2* pout = (uint2*)(out + 4194308);             // 1 MB inside o_wnew; consumed by k_select
    float* o_scal    = out + 4194304;
    float* o_wnew    = out + 4194308;
    float* o_cluster = out + 8388612;
    float* o_embed   = out + 8404996;

    hipMemsetAsync(scal, 0, 64, stream);
    k_pre<<<5248, 256, 0, stream>>>(z, zf, Ah, w, Bh, cs, scal, counts);
    k_gemm_argmin<<<dim3(128, STRIPS), 256, 0, stream>>>(Ah, Bh, pout);
    k_select<<<4096, 256, 0, stream>>>(pout, zf, w, tokrank, counts, dmin);
    k_scan<<<1, 256, 0, stream>>>(counts, offsets);
    k_scatter<<<64, 256, 0, stream>>>(tokrank, offsets, perm);
    k_embed<<<4096, 256, 0, stream>>>(offsets, counts, perm, zf, ea, cs, scal,
                                      o_embed, o_cluster, o_wnew);
    k_post2<<<1088, 256, 0, stream>>>(tokrank, w, counts, dmin, scal, out);
    k_scalars<<<1, 64, 0, stream>>>(scal, o_scal);
}